// Round 12
// baseline (170.718 us; speedup 1.0000x reference)
//
#include <hip/hip_runtime.h>
#include <hip/hip_bf16.h>

#define BB   256
#define SS   2048
#define DIN  32
#define DSL  64
#define KSEL 8

// ws layout: [0, BB*SS) f32 scores  |  then BB*SS*DSL bf16 h1 (TILED)
// h1 tiled layout (elements): elem(r, j) at (r>>6)*4096 + (j>>3)*512 + (r&63)*8 + (j&7)
// d_out layout: sel [B,K,64] | ctx [B,64] | attnW [B,S]  (f32, concat flat)

static __device__ __forceinline__ float bflo(unsigned int u) {
    return __uint_as_float(u << 16);
}
static __device__ __forceinline__ float bfhi(unsigned int u) {
    return __uint_as_float(u & 0xFFFF0000u);
}
static __device__ __forceinline__ unsigned int bf16bits(float f) {
    __hip_bfloat16 h = __float2bfloat16(f);  // RNE
    unsigned short u;
    __builtin_memcpy(&u, &h, 2);
    return (unsigned int)u;
}

// packed f32 FMA, broadcasting LOW half of w to both lanes of the pair:
//   d.lo = a.lo*w.lo + c.lo ; d.hi = a.hi*w.lo + c.hi
static __device__ __forceinline__ float2 pk_fma_e(float2 a, float2 w, float2 c) {
    float2 d;
    asm("v_pk_fma_f32 %0, %1, %2, %3 op_sel:[0,0,0] op_sel_hi:[1,0,1]"
        : "=v"(d) : "v"(a), "v"(w), "v"(c));
    return d;
}
// broadcasting HIGH half of w:
static __device__ __forceinline__ float2 pk_fma_o(float2 a, float2 w, float2 c) {
    float2 d;
    asm("v_pk_fma_f32 %0, %1, %2, %3 op_sel:[0,1,0] op_sel_hi:[1,1,1]"
        : "=v"(d) : "v"(a), "v"(w), "v"(c));
    return d;
}

// ---------------- Kernel 1: h1 (bf16, tiled) + scores (f32) ----------------
// 1024 blocks x 256. 2 slots/lane packed in VGPR pairs; GEMM runs on the
// dual-f32 pipe via v_pk_fma_f32 (157 TF peak vs 78.6 TF scalar).
__global__ __launch_bounds__(256)
void k1_mlp_scores(const float* __restrict__ feats,
                   const float* __restrict__ W1, const float* __restrict__ b1,
                   const float* __restrict__ W2, const float* __restrict__ b2,
                   const float* __restrict__ q,
                   float* __restrict__ scores_ws,
                   unsigned short* __restrict__ h1_ws) {
    // Wl row j (stride 36 floats = 144B, 16B-aligned): [w0..w31, b1j, vj, pad, pad]
    __shared__ float Wl[DSL * 36 + 1];
    const int t = threadIdx.x;

    if (t < DSL) {
        const int j = t;
#pragma unroll
        for (int i = 0; i < DIN; ++i) Wl[j * 36 + i] = W1[i * DSL + j];
        float vj = 0.f;
        for (int d = 0; d < DSL; ++d)
            vj = fmaf(W2[j * DSL + d], q[d] + q[DSL + d], vj);
        Wl[j * 36 + 32] = b1[j];
        Wl[j * 36 + 33] = vj * 0.0625f;  // 0.5 (head mean) * 0.125 (1/sqrt(64))
    } else if (t == DSL) {
        float c0 = 0.f;
        for (int d = 0; d < DSL; ++d)
            c0 = fmaf(b2[d], q[d] + q[DSL + d], c0);
        Wl[DSL * 36] = c0 * 0.0625f;
    }
    __syncthreads();

    const int lane = t & 63;
    const int wave = t >> 6;
    const long base = (long)blockIdx.x * 512 + (long)wave * 128;
    const long rA = base + lane;
    const long rB = base + 64 + lane;
    const long tileA = base >> 6;  // rA's tile; rB's tile = tileA+1

    // load both x rows, interleave into (xA[i], xB[i]) VGPR pairs
    float2 xab[DIN];
    {
        const float4* pa = (const float4*)(feats + rA * DIN);
        const float4* pb = (const float4*)(feats + rB * DIN);
#pragma unroll
        for (int i4 = 0; i4 < DIN / 4; ++i4) {
            float4 va = pa[i4];
            float4 vb = pb[i4];
            xab[4 * i4 + 0] = make_float2(va.x, vb.x);
            xab[4 * i4 + 1] = make_float2(va.y, vb.y);
            xab[4 * i4 + 2] = make_float2(va.z, vb.z);
            xab[4 * i4 + 3] = make_float2(va.w, vb.w);
        }
    }

    const float c0 = Wl[DSL * 36];
    float sA = c0, sB = c0;
    unsigned short* hA = h1_ws + (tileA << 12) + (lane << 3);
    unsigned short* hB = h1_ws + ((tileA + 1) << 12) + (lane << 3);

    for (int jb = 0; jb < 8; ++jb) {
        unsigned int pkA[4], pkB[4];
#pragma unroll
        for (int jo = 0; jo < 8; ++jo) {
            const int j = jb * 8 + jo;
            const float4* wr4 = (const float4*)&Wl[j * 36];
            // 4 independent partial-acc chains, 8 deep each
            float2 a0 = make_float2(0.f, 0.f), a1 = a0, a2 = a0, a3 = a0;
#pragma unroll
            for (int i4 = 0; i4 < DIN / 4; ++i4) {
                float4 w = wr4[i4];                       // 4 weights
                float2 wp0 = make_float2(w.x, w.y);
                float2 wp1 = make_float2(w.z, w.w);
                a0 = pk_fma_e(xab[4 * i4 + 0], wp0, a0);  // w.x
                a1 = pk_fma_o(xab[4 * i4 + 1], wp0, a1);  // w.y
                a2 = pk_fma_e(xab[4 * i4 + 2], wp1, a2);  // w.z
                a3 = pk_fma_o(xab[4 * i4 + 3], wp1, a3);  // w.w
            }
            float2 h2;
            h2.x = (a0.x + a1.x) + (a2.x + a3.x);
            h2.y = (a0.y + a1.y) + (a2.y + a3.y);
            const float2 bv = *(const float2*)&Wl[j * 36 + 32];  // (b1j, vj)
            float ha  = fmaxf(h2.x + bv.x, 0.f);
            float hb2 = fmaxf(h2.y + bv.x, 0.f);
            sA = fmaf(ha, bv.y, sA);
            sB = fmaf(hb2, bv.y, sB);
            if ((jo & 1) == 0) {
                pkA[jo >> 1] = bf16bits(ha);
                pkB[jo >> 1] = bf16bits(hb2);
            } else {
                pkA[jo >> 1] |= bf16bits(ha) << 16;
                pkB[jo >> 1] |= bf16bits(hb2) << 16;
            }
        }
        // coalesced: 64 lanes x 16B = 1KB contiguous per wave store
        *(uint4*)(hA + (jb << 9)) = make_uint4(pkA[0], pkA[1], pkA[2], pkA[3]);
        *(uint4*)(hB + (jb << 9)) = make_uint4(pkB[0], pkB[1], pkB[2], pkB[3]);
    }
    scores_ws[rA] = sA;  // coalesced
    scores_ws[rB] = sB;
}

// ---------------- Kernel 2: softmax + ctx + topk + sel (1024 thr) ----------
#define T2 1024
#define W2C (T2 / 64)  // 16 waves

__global__ __launch_bounds__(T2)
void k2_attend(const float* __restrict__ feats,
               const void* __restrict__ maskp,
               const float* __restrict__ W1, const float* __restrict__ b1,
               const float* __restrict__ W2, const float* __restrict__ b2,
               const float* __restrict__ scores_ws,
               const unsigned short* __restrict__ h1_ws,
               float* __restrict__ sel_out,
               float* __restrict__ ctx_out,
               float* __restrict__ attn_out) {
    __shared__ float scm[SS];          // masked scores (-inf at masked)
    __shared__ float wbuf[SS];         // exp / attnW
    __shared__ float red[W2C * DSL];   // cross-wave reduction scratch
    __shared__ float ubar[DSL];
    __shared__ float wredf[W2C];
    __shared__ float wargv[W2C];
    __shared__ int   wargi[W2C];
    __shared__ int   topidx[KSEL];
    __shared__ int   maskIsByte;
    __shared__ float xsel[KSEL][DIN];
    __shared__ float h1sel[KSEL][DSL];

    const int t = threadIdx.x;
    const int b = blockIdx.x;
    const int lane = t & 63;
    const int wv = t >> 6;

    // --- mask dtype detection: int32 {0,1} has zero bytes at %4!=0 ---
    if (t == 0) maskIsByte = 0;
    __syncthreads();
    {
        unsigned int u = ((const unsigned int*)maskp)[t];  // first 4KB (mask >= 512KB)
        if ((u & 0xFFFFFF00u) != 0u) atomicOr(&maskIsByte, 1);
    }
    __syncthreads();
    const bool mbyte = (maskIsByte != 0);

    // --- Phase A: load + mask scores ---
    for (int s = t; s < SS; s += T2) {
        float v = scores_ws[(size_t)b * SS + s];
        bool mk = mbyte ? (((const unsigned char*)maskp)[(size_t)b * SS + s] != 0)
                        : (((const int*)maskp)[(size_t)b * SS + s] != 0);
        scm[s] = mk ? v : -INFINITY;
    }
    __syncthreads();

    // --- Phase B: masked softmax -> attnW ---
    float lm = -INFINITY;
    for (int s = t; s < SS; s += T2) lm = fmaxf(lm, scm[s]);
#pragma unroll
    for (int o = 1; o < 64; o <<= 1) lm = fmaxf(lm, __shfl_xor(lm, o));
    if (lane == 0) wredf[wv] = lm;
    __syncthreads();
    float m = wredf[0];
#pragma unroll
    for (int i = 1; i < W2C; ++i) m = fmaxf(m, wredf[i]);
    __syncthreads();  // protect wredf before re-use

    float lz = 0.f;
    if (m == -INFINITY) {  // all-masked row: reference -> uniform softmax
        for (int s = t; s < SS; s += T2) wbuf[s] = 1.f;
        lz = (float)(SS / T2);
    } else {
        for (int s = t; s < SS; s += T2) {
            float e = __expf(scm[s] - m);  // exp(-inf)=0 for masked
            wbuf[s] = e;
            lz += e;
        }
    }
#pragma unroll
    for (int o = 1; o < 64; o <<= 1) lz += __shfl_xor(lz, o);
    if (lane == 0) wredf[wv] = lz;
    __syncthreads();
    float Z = wredf[0];
#pragma unroll
    for (int i = 1; i < W2C; ++i) Z += wredf[i];
    const float invZ = 1.f / Z;
    for (int s = t; s < SS; s += T2) {
        float w = wbuf[s] * invZ;
        wbuf[s] = w;
        attn_out[(size_t)b * SS + s] = w;
    }
    __syncthreads();

    // --- Phase C: u[j] = sum_s attnW[s]*h1[s][j]  (tiled bf16 h1) ---
    const int jb = t & 7;        // j-block: j = jb*8 + m
    const int sg = t >> 3;       // 0..127
    float u8[8] = {0.f, 0.f, 0.f, 0.f, 0.f, 0.f, 0.f, 0.f};
    const unsigned short* hb =
        h1_ws + (size_t)b * (SS * DSL)
              + ((size_t)(sg >> 6) << 12) + (jb << 9) + ((sg & 63) << 3);
    for (int k = 0; k < SS / 128; ++k) {  // 16 iters
        float w = wbuf[sg + (k << 7)];
        uint4 hv = *(const uint4*)(hb + ((size_t)k << 13));
        u8[0] = fmaf(w, bflo(hv.x), u8[0]);
        u8[1] = fmaf(w, bfhi(hv.x), u8[1]);
        u8[2] = fmaf(w, bflo(hv.y), u8[2]);
        u8[3] = fmaf(w, bfhi(hv.y), u8[3]);
        u8[4] = fmaf(w, bflo(hv.z), u8[4]);
        u8[5] = fmaf(w, bfhi(hv.z), u8[5]);
        u8[6] = fmaf(w, bflo(hv.w), u8[6]);
        u8[7] = fmaf(w, bfhi(hv.w), u8[7]);
    }
    // sum the 8 sg-subgroups within each wave (lane bits 3..5)
#pragma unroll
    for (int o = 8; o <= 32; o <<= 1) {
#pragma unroll
        for (int mm = 0; mm < 8; ++mm) u8[mm] += __shfl_xor(u8[mm], o);
    }
    if (lane < 8) {
#pragma unroll
        for (int mm = 0; mm < 8; ++mm) red[wv * DSL + lane * 8 + mm] = u8[mm];
    }
    __syncthreads();
    if (t < DSL) {
        float acc = 0.f;
#pragma unroll
        for (int w2i = 0; w2i < W2C; ++w2i) acc += red[w2i * DSL + t];
        ubar[t] = acc;
    }
    __syncthreads();

    // --- Phase D: ctx = u @ W2 + b2 (16 waves, 4 j's each) ---
    {
        float acc = (wv == 0) ? b2[lane] : 0.f;
        for (int jj = wv * 4; jj < wv * 4 + 4; ++jj)
            acc = fmaf(ubar[jj], W2[jj * DSL + lane], acc);
        red[wv * DSL + lane] = acc;
    }
    __syncthreads();
    if (t < DSL) {
        float acc = 0.f;
#pragma unroll
        for (int w2i = 0; w2i < W2C; ++w2i) acc += red[w2i * DSL + t];
        ctx_out[(size_t)b * DSL + t] = acc;
    }

    // --- Phase E: top-K (descending value, ties -> lower index) ---
    for (int k = 0; k < KSEL; ++k) {
        // seed with s=t so an all -inf row still yields valid indices
        float bvv = scm[t];
        int bi = t;
#pragma unroll
        for (int kk = 1; kk < SS / T2; ++kk) {  // ascending index
            int s = t + kk * T2;
            float v = scm[s];
            if (v > bvv) { bvv = v; bi = s; }
        }
#pragma unroll
        for (int o = 1; o < 64; o <<= 1) {
            float ov = __shfl_xor(bvv, o);
            int oi = __shfl_xor(bi, o);
            if (ov > bvv || (ov == bvv && oi < bi)) { bvv = ov; bi = oi; }
        }
        if (lane == 0) { wargv[wv] = bvv; wargi[wv] = bi; }
        __syncthreads();
        if (t == 0) {
            float Bv = wargv[0]; int Bi = wargi[0];
            for (int w2i = 1; w2i < W2C; ++w2i) {
                float ov = wargv[w2i]; int oi = wargi[w2i];
                if (ov > Bv || (ov == Bv && oi < Bi)) { Bv = ov; Bi = oi; }
            }
            topidx[k] = Bi;
            scm[Bi] = -INFINITY;
        }
        __syncthreads();
    }

    // --- Phase F: sel = full f32 MLP recompute of the K selected rows ---
    if (t < KSEL * DIN) {
        int k = t >> 5, i = t & 31;
        xsel[k][i] = feats[((size_t)b * SS + topidx[k]) * DIN + i];
    }
    __syncthreads();
    if (wv < KSEL) {
        const int k = wv;
        float h = b1[lane];
#pragma unroll
        for (int i = 0; i < DIN; ++i) h = fmaf(xsel[k][i], W1[i * DSL + lane], h);
        h1sel[k][lane] = fmaxf(h, 0.f);
    }
    __syncthreads();
    if (wv < KSEL) {
        const int k = wv;
        float acc = b2[lane];
        for (int jj = 0; jj < DSL; ++jj)
            acc = fmaf(h1sel[k][jj], W2[jj * DSL + lane], acc);
        sel_out[((size_t)b * KSEL + k) * DSL + lane] = acc;
    }
}

extern "C" void kernel_launch(void* const* d_in, const int* in_sizes, int n_in,
                              void* d_out, int out_size, void* d_ws, size_t ws_size,
                              hipStream_t stream) {
    const float* feats = (const float*)d_in[0];
    const void*  mask  = d_in[1];
    const float* W1 = (const float*)d_in[2];
    const float* b1 = (const float*)d_in[3];
    const float* W2 = (const float*)d_in[4];
    const float* b2 = (const float*)d_in[5];
    const float* q  = (const float*)d_in[6];

    float* scores_ws = (float*)d_ws;
    unsigned short* h1_ws =
        (unsigned short*)((char*)d_ws + (size_t)BB * SS * sizeof(float));

    float* sel_out  = (float*)d_out;                       // B*K*64
    float* ctx_out  = sel_out + (size_t)BB * KSEL * DSL;   // B*64
    float* attn_out = ctx_out + (size_t)BB * DSL;          // B*S

    hipLaunchKernelGGL(k1_mlp_scores, dim3(BB * SS / 512), dim3(256), 0, stream,
                       feats, W1, b1, W2, b2, q, scores_ws, h1_ws);
    hipLaunchKernelGGL(k2_attend, dim3(BB), dim3(T2), 0, stream,
                       feats, mask, W1, b1, W2, b2, scores_ws, h1_ws,
                       sel_out, ctx_out, attn_out);
}